// Round 3
// baseline (563.483 us; speedup 1.0000x reference)
//
#include <hip/hip_runtime.h>

#define NB 256   // batch
#define NT 512   // time steps
#define ND 128   // input dim
#define NU 128   // hidden dim
#define NC 64    // classes
#define ROWS 16          // batch rows per block
#define NBLK (NB / ROWS) // 16 blocks
#define PITCH 136        // Y LDS row pitch in halfs (272 B: 16B-aligned, low-conflict)

typedef _Float16 half8 __attribute__((ext_vector_type(8)));
typedef float f32x4 __attribute__((ext_vector_type(4)));

#define MFMA(a, b, c) __builtin_amdgcn_mfma_f32_16x16x32_f16((a), (b), (c), 0, 0, 0)

// tanh(x) from pre-scaled s=2x: tanh = 1 - 2/(e^s + 1). exp->inf/0 limits exact.
__device__ __forceinline__ float tanh_s(float s) {
  float e = __expf(s);
  return fmaf(-2.0f, __builtin_amdgcn_rcpf(e + 1.0f), 1.0f);
}

// LDS-only barrier: drain LDS ops, do NOT drain vmcnt (keeps x-prefetch and
// out-stores in flight across steps).
__device__ __forceinline__ void wg_barrier() {
  asm volatile("s_waitcnt lgkmcnt(0)\n\ts_barrier" ::: "memory");
}

// B-operand fragment: lane holds col n, k = k0..k0+7 (gemm_bt-style layout).
__device__ __forceinline__ half8 wfrag(const float* W, int ldw, int k0, int col,
                                       float scale) {
  half8 h;
#pragma unroll
  for (int j = 0; j < 8; ++j) h[j] = (_Float16)(W[(k0 + j) * ldw + col] * scale);
  return h;
}

__device__ __forceinline__ half8 cvt8(const float4& a, const float4& b) {
  half8 h;
  h[0] = (_Float16)a.x; h[1] = (_Float16)a.y; h[2] = (_Float16)a.z; h[3] = (_Float16)a.w;
  h[4] = (_Float16)b.x; h[5] = (_Float16)b.y; h[6] = (_Float16)b.z; h[7] = (_Float16)b.w;
  return h;
}

// Block: 4 waves, 16 batch rows. Wave w owns hidden cols [32w,32w+32) (2 MFMA
// col-tiles) and classifier col-tile [16w,16w+16).
// Per step: R=8 MFMA, C=4 MFMA, H(t+2)=8 MFMA; one lgkm barrier.
__global__ __launch_bounds__(256, 1) void rnn_mfma(
    const float* __restrict__ x,   // (B,T,D)
    const float* __restrict__ W1,  // (D,U)
    const float* __restrict__ b1v, // (U)
    const float* __restrict__ W2,  // (U,U)
    const float* __restrict__ b2v, // (U)
    const float* __restrict__ Wc,  // (U,C)
    const float* __restrict__ bcv, // (C)
    float* __restrict__ out)       // (B,T,C)
{
  __shared__ _Float16 Ylds[2 * ROWS * PITCH];  // y_t double-buffered, f16

  const int tid = (int)threadIdx.x;
  const int w   = tid >> 6;       // wave 0..3
  const int L   = tid & 63;
  const int c16 = L & 15;         // MFMA lane col / A-row index
  const int q   = L >> 4;         // quad
  const int b0  = (int)blockIdx.x * ROWS;

  // ---- zero Y LDS (both buffers incl. padding) ----
  for (int i = tid; i < (2 * ROWS * PITCH) / 2; i += 256) ((unsigned*)Ylds)[i] = 0u;
  __syncthreads();

  // ---- weight fragments (B-operand layout), W1/W2 pre-scaled by 2 ----
  const int cb = 32 * w;                 // hidden col base for this wave
  const int cc0 = 16 * w;                // classifier col base
  half8 B2f[2][4], B1f[2][4], Bcf[4];
#pragma unroll
  for (int k4 = 0; k4 < 4; ++k4) {
    const int k0 = 32 * k4 + 8 * q;
#pragma unroll
    for (int ct = 0; ct < 2; ++ct) {
      B2f[ct][k4] = wfrag(W2, NU, k0, cb + 16 * ct + c16, 2.0f);
      B1f[ct][k4] = wfrag(W1, NU, k0, cb + 16 * ct + c16, 2.0f);
    }
    Bcf[k4] = wfrag(Wc, NC, k0, cc0 + c16, 1.0f);
  }
  const float b2s0 = b2v[cb + c16] * 2.0f;
  const float b2s1 = b2v[cb + 16 + c16] * 2.0f;
  const float b1s0 = b1v[cb + c16] * 2.0f;
  const float b1s1 = b1v[cb + 16 + c16] * 2.0f;
  const float bcs  = bcv[cc0 + c16];

  // x pointer for this lane's A-row (batch row b0+c16), k-offset 8q baked in
  const float* xp = x + (size_t)(b0 + c16) * NT * ND + 8 * q;

  // ---- H prologue: th for t=0,1 from direct x loads ----
  f32x4 thE0, thE1, thO0, thO1;
  {
#pragma unroll
    for (int t0 = 0; t0 < 2; ++t0) {
      half8 xf[4];
#pragma unroll
      for (int k4 = 0; k4 < 4; ++k4) {
        float4 a = *(const float4*)(xp + (size_t)t0 * ND + 32 * k4);
        float4 b = *(const float4*)(xp + (size_t)t0 * ND + 32 * k4 + 4);
        xf[k4] = cvt8(a, b);
      }
      f32x4 h0 = {b1s0, b1s0, b1s0, b1s0};
      f32x4 h1 = {b1s1, b1s1, b1s1, b1s1};
#pragma unroll
      for (int k4 = 0; k4 < 4; ++k4) {
        h0 = MFMA(xf[k4], B1f[0][k4], h0);
        h1 = MFMA(xf[k4], B1f[1][k4], h1);
      }
      f32x4 t0v, t1v;
#pragma unroll
      for (int r = 0; r < 4; ++r) { t0v[r] = tanh_s(h0[r]); t1v[r] = tanh_s(h1[r]); }
      if (t0 == 0) { thE0 = t0v; thE1 = t1v; } else { thO0 = t0v; thO1 = t1v; }
    }
  }

  // ---- x raw prefetch: slot A holds x(2), slot B holds x(3) (2-iter flight) ----
  float4 xrA[4][2], xrB[4][2];
#pragma unroll
  for (int k4 = 0; k4 < 4; ++k4) {
    xrA[k4][0] = *(const float4*)(xp + (size_t)2 * ND + 32 * k4);
    xrA[k4][1] = *(const float4*)(xp + (size_t)2 * ND + 32 * k4 + 4);
    xrB[k4][0] = *(const float4*)(xp + (size_t)3 * ND + 32 * k4);
    xrB[k4][1] = *(const float4*)(xp + (size_t)3 * ND + 32 * k4 + 4);
  }

// One recurrence step. XR_ holds x(t+2) raw; refilled with x(t+4).
// TH0_/TH1_ hold tanh(h_t) per col-tile; refilled with tanh(h_{t+2}).
#define BODY(T_, XR_, TH0_, TH1_)                                              \
  {                                                                            \
    const int t_ = (T_);                                                       \
    const int bufR = ((t_ + 1) & 1) * (ROWS * PITCH);                          \
    const int bufW = (t_ & 1) * (ROWS * PITCH);                                \
    wg_barrier();                                                              \
    /* y_{t-1} A-frags (zeros for t=0) */                                      \
    const _Float16* yb = Ylds + bufR + c16 * PITCH + 8 * q;                    \
    half8 yA0 = *(const half8*)(yb + 0);                                       \
    half8 yA1 = *(const half8*)(yb + 32);                                      \
    half8 yA2 = *(const half8*)(yb + 64);                                      \
    half8 yA3 = *(const half8*)(yb + 96);                                      \
    /* overlap read latency: cvt x(t+2), issue loads x(t+4) */                 \
    half8 xf0 = cvt8(XR_[0][0], XR_[0][1]);                                    \
    half8 xf1 = cvt8(XR_[1][0], XR_[1][1]);                                    \
    half8 xf2 = cvt8(XR_[2][0], XR_[2][1]);                                    \
    half8 xf3 = cvt8(XR_[3][0], XR_[3][1]);                                    \
    {                                                                          \
      int tl = t_ + 4; tl = tl < NT ? tl : NT - 1;                             \
      _Pragma("unroll") for (int k4 = 0; k4 < 4; ++k4) {                       \
        XR_[k4][0] = *(const float4*)(xp + (size_t)tl * ND + 32 * k4);         \
        XR_[k4][1] = *(const float4*)(xp + (size_t)tl * ND + 32 * k4 + 4);     \
      }                                                                        \
    }                                                                          \
    /* R = y_{t-1} @ W2*2 + b2*2 */                                            \
    f32x4 r0 = {b2s0, b2s0, b2s0, b2s0};                                       \
    f32x4 r1 = {b2s1, b2s1, b2s1, b2s1};                                       \
    r0 = MFMA(yA0, B2f[0][0], r0);  r1 = MFMA(yA0, B2f[1][0], r1);             \
    r0 = MFMA(yA1, B2f[0][1], r0);  r1 = MFMA(yA1, B2f[1][1], r1);             \
    r0 = MFMA(yA2, B2f[0][2], r0);  r1 = MFMA(yA2, B2f[1][2], r1);             \
    r0 = MFMA(yA3, B2f[0][3], r0);  r1 = MFMA(yA3, B2f[1][3], r1);             \
    /* classifier: out[t-1] = y_{t-1} @ Wc + bc */                             \
    f32x4 co = {bcs, bcs, bcs, bcs};                                           \
    co = MFMA(yA0, Bcf[0], co);                                                \
    co = MFMA(yA1, Bcf[1], co);                                                \
    co = MFMA(yA2, Bcf[2], co);                                                \
    co = MFMA(yA3, Bcf[3], co);                                                \
    /* y_t = tanh(h_t) + tanh(r) -> f16 -> LDS (C-layout scatter) */           \
    _Pragma("unroll") for (int r = 0; r < 4; ++r) {                            \
      float y0 = TH0_[r] + tanh_s(r0[r]);                                      \
      float y1 = TH1_[r] + tanh_s(r1[r]);                                      \
      Ylds[bufW + (4 * q + r) * PITCH + cb + c16]      = (_Float16)y0;         \
      Ylds[bufW + (4 * q + r) * PITCH + cb + 16 + c16] = (_Float16)y1;         \
    }                                                                          \
    /* H(t+2) -> th (refill after consumption) */                              \
    {                                                                          \
      f32x4 h0 = {b1s0, b1s0, b1s0, b1s0};                                     \
      f32x4 h1 = {b1s1, b1s1, b1s1, b1s1};                                     \
      h0 = MFMA(xf0, B1f[0][0], h0);  h1 = MFMA(xf0, B1f[1][0], h1);           \
      h0 = MFMA(xf1, B1f[0][1], h0);  h1 = MFMA(xf1, B1f[1][1], h1);           \
      h0 = MFMA(xf2, B1f[0][2], h0);  h1 = MFMA(xf2, B1f[1][2], h1);           \
      h0 = MFMA(xf3, B1f[0][3], h0);  h1 = MFMA(xf3, B1f[1][3], h1);           \
      _Pragma("unroll") for (int r = 0; r < 4; ++r) {                          \
        TH0_[r] = tanh_s(h0[r]);                                               \
        TH1_[r] = tanh_s(h1[r]);                                               \
      }                                                                        \
    }                                                                          \
    /* store out[t-1] (C-layout: row=4q+r, col=cc0+c16) */                     \
    if (t_ >= 1) {                                                             \
      _Pragma("unroll") for (int r = 0; r < 4; ++r)                            \
        out[((size_t)(b0 + 4 * q + r) * NT + (t_ - 1)) * NC + cc0 + c16] = co[r]; \
    }                                                                          \
  }

#pragma unroll 1
  for (int t = 0; t < NT; t += 2) {
    BODY(t, xrA, thE0, thE1)
    BODY(t + 1, xrB, thO0, thO1)
  }

  // ---- epilogue: out[NT-1] from y_{NT-1} (in buf[(NT-1)&1]) ----
  {
    wg_barrier();
    const _Float16* yb = Ylds + ((NT - 1) & 1) * (ROWS * PITCH) + c16 * PITCH + 8 * q;
    half8 yA0 = *(const half8*)(yb + 0);
    half8 yA1 = *(const half8*)(yb + 32);
    half8 yA2 = *(const half8*)(yb + 64);
    half8 yA3 = *(const half8*)(yb + 96);
    f32x4 co = {bcs, bcs, bcs, bcs};
    co = MFMA(yA0, Bcf[0], co);
    co = MFMA(yA1, Bcf[1], co);
    co = MFMA(yA2, Bcf[2], co);
    co = MFMA(yA3, Bcf[3], co);
#pragma unroll
    for (int r = 0; r < 4; ++r)
      out[((size_t)(b0 + 4 * q + r) * NT + (NT - 1)) * NC + cc0 + c16] = co[r];
  }
}

extern "C" void kernel_launch(void* const* d_in, const int* in_sizes, int n_in,
                              void* d_out, int out_size, void* d_ws, size_t ws_size,
                              hipStream_t stream) {
  (void)in_sizes; (void)n_in; (void)d_ws; (void)ws_size; (void)out_size;
  const float* x   = (const float*)d_in[0];
  const float* W1  = (const float*)d_in[1];
  const float* b1v = (const float*)d_in[2];
  const float* W2  = (const float*)d_in[3];
  const float* b2v = (const float*)d_in[4];
  const float* Wc  = (const float*)d_in[5];
  const float* bcv = (const float*)d_in[6];
  float* out = (float*)d_out;

  hipLaunchKernelGGL(rnn_mfma, dim3(NBLK), dim3(256), 0, stream,
                     x, W1, b1v, W2, b2v, Wc, bcv, out);
}